// Round 18
// baseline (298.994 us; speedup 1.0000x reference)
//
#include <hip/hip_runtime.h>
#include <hip/hip_bf16.h>
#include <stdint.h>

// MHA forward: B=4, S=2048, D=512, H=8, HD=64. f32 in/out, bf16 MFMA internally.
// out0 = out [B,S,D] f32, out1 = attn [B,H,S,S] f32 (concatenated in d_out).
// k_attn: Q-block 64 rows (4 waves x 16), grid (32,32), SINGLE-buffered
// kv-64 chunks (18.4 KB LDS) + launch_bounds(256,8) -> 8 blocks/CU
// (32 waves/CU, VGPR cap 64 = r11-measured exact fit). Register prefetch;
// lgkm-only barriers (global loads/nt stores never drained in-loop).

typedef __attribute__((ext_vector_type(8))) short bf16x8;
typedef __attribute__((ext_vector_type(4))) short bf16x4;
typedef __attribute__((ext_vector_type(4))) float f32x4;

#define MFMA16(a, b, c) __builtin_amdgcn_mfma_f32_16x16x32_bf16((a), (b), (c), 0, 0, 0)

__device__ __forceinline__ unsigned short f2bf(float f) {
  unsigned u = __float_as_uint(f);
  u += 0x7FFFu + ((u >> 16) & 1u);   // RNE
  return (unsigned short)(u >> 16);
}
__device__ __forceinline__ float bf2f(unsigned short u) {
  return __uint_as_float(((unsigned)u) << 16);
}

// Barrier draining ONLY LDS ops; global loads / nt stores stay in flight.
__device__ __forceinline__ void lds_barrier() {
  asm volatile("s_waitcnt lgkmcnt(0)" ::: "memory");
  __builtin_amdgcn_s_barrier();
}

// ---------------------------------------------------------------------------
// Kernel 1: fused QKV projection. z = 0,1,2 -> q,k,v.
// q,k written as [B,H,S,HD] bf16; v written transposed [B,H,HD,S] bf16.
// ---------------------------------------------------------------------------
__global__ __launch_bounds__(256) void k_proj_qkv(
    const float* __restrict__ q_in, const float* __restrict__ k_in,
    const float* __restrict__ v_in,
    const float* __restrict__ Wq, const float* __restrict__ bq,
    const float* __restrict__ Wk, const float* __restrict__ bk,
    const float* __restrict__ Wv, const float* __restrict__ bv,
    unsigned short* __restrict__ q_ws, unsigned short* __restrict__ k_ws,
    unsigned short* __restrict__ vt_ws)
{
  const int z = blockIdx.z;
  const float* X    = (z == 0) ? q_in : (z == 1) ? k_in : v_in;
  const float* W    = (z == 0) ? Wq   : (z == 1) ? Wk   : Wv;
  const float* bias = (z == 0) ? bq   : (z == 1) ? bk   : bv;
  unsigned short* out = (z == 0) ? q_ws : (z == 1) ? k_ws : vt_ws;

  __shared__ unsigned short As[128][72];
  __shared__ unsigned short Bs[128][72];

  const int t = threadIdx.x;
  const int lane = t & 63;
  const int w = t >> 6;
  const int wr = w >> 1, wc = w & 1;
  const int mbase = blockIdx.x * 128;
  const int nbase = blockIdx.y * 128;

  f32x4 acc[4][4] = {};

  for (int kb = 0; kb < 512; kb += 64) {
    __syncthreads();
#pragma unroll
    for (int i = 0; i < 4; ++i) {
      int chunk = i * 256 + t;
      int row = chunk >> 3;
      int c8 = (chunk & 7) * 8;
      const float* ga = X + (size_t)(mbase + row) * 512 + kb + c8;
      float4 a0 = *(const float4*)ga;
      float4 a1 = *(const float4*)(ga + 4);
      bf16x8 pa;
      pa[0] = (short)f2bf(a0.x); pa[1] = (short)f2bf(a0.y);
      pa[2] = (short)f2bf(a0.z); pa[3] = (short)f2bf(a0.w);
      pa[4] = (short)f2bf(a1.x); pa[5] = (short)f2bf(a1.y);
      pa[6] = (short)f2bf(a1.z); pa[7] = (short)f2bf(a1.w);
      *(bf16x8*)&As[row][c8] = pa;
      const float* gb = W + (size_t)(nbase + row) * 512 + kb + c8;
      float4 b0 = *(const float4*)gb;
      float4 b1 = *(const float4*)(gb + 4);
      bf16x8 pb;
      pb[0] = (short)f2bf(b0.x); pb[1] = (short)f2bf(b0.y);
      pb[2] = (short)f2bf(b0.z); pb[3] = (short)f2bf(b0.w);
      pb[4] = (short)f2bf(b1.x); pb[5] = (short)f2bf(b1.y);
      pb[6] = (short)f2bf(b1.z); pb[7] = (short)f2bf(b1.w);
      *(bf16x8*)&Bs[row][c8] = pb;
    }
    __syncthreads();
#pragma unroll
    for (int kk = 0; kk < 64; kk += 32) {
      bf16x8 af[4], bfr[4];
#pragma unroll
      for (int mi = 0; mi < 4; ++mi)
        af[mi] = *(const bf16x8*)&As[wr * 64 + mi * 16 + (lane & 15)][kk + (lane >> 4) * 8];
#pragma unroll
      for (int ni = 0; ni < 4; ++ni)
        bfr[ni] = *(const bf16x8*)&Bs[wc * 64 + ni * 16 + (lane & 15)][kk + (lane >> 4) * 8];
#pragma unroll
      for (int mi = 0; mi < 4; ++mi)
#pragma unroll
        for (int ni = 0; ni < 4; ++ni)
          acc[mi][ni] = MFMA16(af[mi], bfr[ni], acc[mi][ni]);
    }
  }

#pragma unroll
  for (int ni = 0; ni < 4; ++ni) {
    int n = nbase + wc * 64 + ni * 16 + (lane & 15);
    float bv_ = bias[n];
    int h = n >> 6, hd = n & 63;
#pragma unroll
    for (int mi = 0; mi < 4; ++mi) {
#pragma unroll
      for (int i = 0; i < 4; ++i) {
        int m = mbase + wr * 64 + mi * 16 + (lane >> 4) * 4 + i;
        int b_ = m >> 11, s = m & 2047;
        float val = acc[mi][ni][i] + bv_;
        size_t off;
        if (z < 2) off = ((size_t)(b_ * 8 + h) * 2048 + s) * 64 + hd;      // [B,H,S,HD]
        else       off = ((size_t)(b_ * 8 + h) * 64 + hd) * 2048 + s;      // [B,H,HD,S]
        out[off] = f2bf(val);
      }
    }
  }
}

// ---------------------------------------------------------------------------
// Kernel 2: attention. Grid (32,32), 256 thr (4 waves). Single-buffered
// 64-kv chunks: regs prefetch -> LDS write -> lds_barrier -> compute ->
// lds_barrier. LDS 18.4 KB + launch_bounds(256,8) -> 8 blocks/CU.
// Wave w owns q-rows [qbase + w*16, +16). Swapped QK^T: mfma(K,Q) ->
// lane (lo=q,hi) holds 4 consecutive kv for its own q row.
// ---------------------------------------------------------------------------
__global__ __launch_bounds__(256, 8) void k_attn(
    const unsigned short* __restrict__ q_ws, const unsigned short* __restrict__ k_ws,
    const unsigned short* __restrict__ vt_ws, unsigned short* __restrict__ o_ws,
    float* __restrict__ attn_out)
{
  __shared__ unsigned short Ks[64][72];      // 9216 B
  __shared__ unsigned short Vs[64][72];      // 9216 B

  const int t = threadIdx.x;
  const int lane = t & 63;
  const int w = t >> 6;            // 0..3
  const int lo = lane & 15;
  const int hi = lane >> 4;        // 0..3
  const int bh = blockIdx.y;       // 0..31
  const int qbase = blockIdx.x * 64;
  const int qw = qbase + w * 16;   // wave's q rows
  const size_t qk_base = (size_t)bh * 2048 * 64;

  // Q fragments (B operand: col = q = lo, d = hi*8 + j)
  bf16x8 qf0 = *(const bf16x8*)(q_ws + qk_base + (size_t)(qw + lo) * 64 + hi * 8);
  bf16x8 qf1 = *(const bf16x8*)(q_ws + qk_base + (size_t)(qw + lo) * 64 + 32 + hi * 8);

  // ---------------- pass A: row sums ----------------
  float srow = 0.f;
  {
    bf16x8 gk[2];
#pragma unroll
    for (int i = 0; i < 2; ++i) {
      int flat = t + i * 256;
      gk[i] = *(const bf16x8*)(k_ws + qk_base + (size_t)(flat >> 3) * 64 + (flat & 7) * 8);
    }
    for (int c = 0; c < 32; ++c) {
#pragma unroll
      for (int i = 0; i < 2; ++i) {
        int flat = t + i * 256;
        *(bf16x8*)&Ks[flat >> 3][(flat & 7) * 8] = gk[i];
      }
      if (c < 31) {
#pragma unroll
        for (int i = 0; i < 2; ++i) {
          int flat = t + i * 256;
          gk[i] = *(const bf16x8*)(k_ws + qk_base +
                                   (size_t)((c + 1) * 64 + (flat >> 3)) * 64 + (flat & 7) * 8);
        }
      }
      lds_barrier();
#pragma unroll
      for (int t2 = 0; t2 < 4; ++t2) {
        bf16x8 kf0 = *(const bf16x8*)&Ks[t2 * 16 + lo][hi * 8];
        bf16x8 kf1 = *(const bf16x8*)&Ks[t2 * 16 + lo][32 + hi * 8];
        f32x4 cv = {};
        cv = MFMA16(kf0, qf0, cv);
        cv = MFMA16(kf1, qf1, cv);
        srow += __expf(cv[0] * 0.125f) + __expf(cv[1] * 0.125f) +
                __expf(cv[2] * 0.125f) + __expf(cv[3] * 0.125f);
      }
      lds_barrier();   // compute reads done before next chunk's writes
    }
  }
  srow += __shfl_xor(srow, 16, 64);
  srow += __shfl_xor(srow, 32, 64);
  const float rv = 1.0f / srow;    // valid for q = lo in all lanes

  // ---------------- pass B: PV + attn stores ----------------
  f32x4 o_acc[4] = {};             // [hdt]: rows q=qw+hi*4+i, col hd=hdt*16+lo
  {
    float* ao = attn_out + (size_t)bh * 2048 * 2048 +
                (size_t)(qw + lo) * 2048 + hi * 4;
    bf16x8 gk[2], gv[2];
#pragma unroll
    for (int i = 0; i < 2; ++i) {
      int flat = t + i * 256;
      gk[i] = *(const bf16x8*)(k_ws + qk_base + (size_t)(flat >> 3) * 64 + (flat & 7) * 8);
      gv[i] = *(const bf16x8*)(vt_ws + (size_t)(bh * 64 + (flat >> 3)) * 2048 + (flat & 7) * 8);
    }
    for (int c = 0; c < 32; ++c) {
#pragma unroll
      for (int i = 0; i < 2; ++i) {
        int flat = t + i * 256;
        *(bf16x8*)&Ks[flat >> 3][(flat & 7) * 8] = gk[i];
        *(bf16x8*)&Vs[flat >> 3][(flat & 7) * 8] = gv[i];
      }
      if (c < 31) {
#pragma unroll
        for (int i = 0; i < 2; ++i) {
          int flat = t + i * 256;
          gk[i] = *(const bf16x8*)(k_ws + qk_base +
                                   (size_t)((c + 1) * 64 + (flat >> 3)) * 64 + (flat & 7) * 8);
          gv[i] = *(const bf16x8*)(vt_ws + (size_t)(bh * 64 + (flat >> 3)) * 2048 +
                                   (c + 1) * 64 + (flat & 7) * 8);
        }
      }
      lds_barrier();

      unsigned pk[4][2];           // normalized bf16 pairs per t2-tile
#pragma unroll
      for (int t2 = 0; t2 < 4; ++t2) {
        bf16x8 kf0 = *(const bf16x8*)&Ks[t2 * 16 + lo][hi * 8];
        bf16x8 kf1 = *(const bf16x8*)&Ks[t2 * 16 + lo][32 + hi * 8];
        f32x4 cv = {};
        cv = MFMA16(kf0, qf0, cv);
        cv = MFMA16(kf1, qf1, cv);
        float n0 = __expf(cv[0] * 0.125f) * rv;
        float n1 = __expf(cv[1] * 0.125f) * rv;
        float n2 = __expf(cv[2] * 0.125f) * rv;
        float n3 = __expf(cv[3] * 0.125f) * rv;
        // attn store: f32x4, q-row = lo, kv = c*64 + t2*16 + hi*4
        f32x4 s; s[0] = n0; s[1] = n1; s[2] = n2; s[3] = n3;
        __builtin_nontemporal_store(s, (f32x4*)(ao + c * 64 + t2 * 16));
        pk[t2][0] = (unsigned)f2bf(n0) | ((unsigned)f2bf(n1) << 16);
        pk[t2][1] = (unsigned)f2bf(n2) | ((unsigned)f2bf(n3) << 16);
      }
      // PV: two K=32 MFMAs per hdt (ks=0: t2 0,1; ks=1: t2 2,3)
#pragma unroll
      for (int ks = 0; ks < 2; ++ks) {
        bf16x8 pa8;
        pa8[0] = (short)(pk[2 * ks][0] & 0xffffu);
        pa8[1] = (short)(pk[2 * ks][0] >> 16);
        pa8[2] = (short)(pk[2 * ks][1] & 0xffffu);
        pa8[3] = (short)(pk[2 * ks][1] >> 16);
        pa8[4] = (short)(pk[2 * ks + 1][0] & 0xffffu);
        pa8[5] = (short)(pk[2 * ks + 1][0] >> 16);
        pa8[6] = (short)(pk[2 * ks + 1][1] & 0xffffu);
        pa8[7] = (short)(pk[2 * ks + 1][1] >> 16);
#pragma unroll
        for (int hdt = 0; hdt < 4; ++hdt) {
          bf16x4 v4a = *(const bf16x4*)&Vs[hdt * 16 + lo][ks * 32 + hi * 4];
          bf16x4 v4b = *(const bf16x4*)&Vs[hdt * 16 + lo][ks * 32 + 16 + hi * 4];
          bf16x8 vb8;
          vb8[0] = v4a[0]; vb8[1] = v4a[1]; vb8[2] = v4a[2]; vb8[3] = v4a[3];
          vb8[4] = v4b[0]; vb8[5] = v4b[1]; vb8[6] = v4b[2]; vb8[7] = v4b[3];
          o_acc[hdt] = MFMA16(pa8, vb8, o_acc[hdt]);
        }
      }
      lds_barrier();
    }
  }

  // ---------------- O write (already normalized) ----------------
  {
    const int b_ = bh >> 3, h = bh & 7;
#pragma unroll
    for (int hdt = 0; hdt < 4; ++hdt)
#pragma unroll
      for (int i = 0; i < 4; ++i) {
        int q = qw + hi * 4 + i;
        o_ws[((size_t)(b_ * 2048) + q) * 512 + h * 64 + hdt * 16 + lo] =
            f2bf(o_acc[hdt][i]);
      }
  }
}

// ---------------------------------------------------------------------------
// Kernel 3: output projection, f32 out.
// ---------------------------------------------------------------------------
__global__ __launch_bounds__(256) void k_proj_out(
    const unsigned short* __restrict__ Ao, const float* __restrict__ Wo,
    const float* __restrict__ bo, float* __restrict__ outp)
{
  __shared__ unsigned short As[128][72];
  __shared__ unsigned short Bs[128][72];

  const int t = threadIdx.x;
  const int lane = t & 63;
  const int w = t >> 6;
  const int wr = w >> 1, wc = w & 1;
  const int mbase = blockIdx.x * 128;
  const int nbase = blockIdx.y * 128;

  f32x4 acc[4][4] = {};

  for (int kb = 0; kb < 512; kb += 64) {
    __syncthreads();
#pragma unroll
    for (int i = 0; i < 4; ++i) {
      int chunk = i * 256 + t;
      int row = chunk >> 3;
      int c8 = (chunk & 7) * 8;
      *(bf16x8*)&As[row][c8] =
          *(const bf16x8*)(Ao + (size_t)(mbase + row) * 512 + kb + c8);
      const float* gb = Wo + (size_t)(nbase + row) * 512 + kb + c8;
      float4 b0 = *(const float4*)gb;
      float4 b1 = *(const float4*)(gb + 4);
      bf16x8 pb;
      pb[0] = (short)f2bf(b0.x); pb[1] = (short)f2bf(b0.y);
      pb[2] = (short)f2bf(b0.z); pb[3] = (short)f2bf(b0.w);
      pb[4] = (short)f2bf(b1.x); pb[5] = (short)f2bf(b1.y);
      pb[6] = (short)f2bf(b1.z); pb[7] = (short)f2bf(b1.w);
      *(bf16x8*)&Bs[row][c8] = pb;
    }
    __syncthreads();
#pragma unroll
    for (int kk = 0; kk < 64; kk += 32) {
      bf16x8 af[4], bfr[4];
#pragma unroll
      for (int mi = 0; mi < 4; ++mi)
        af[mi] = *(const bf16x8*)&As[wr * 64 + mi * 16 + (lane & 15)][kk + (lane >> 4) * 8];
#pragma unroll
      for (int ni = 0; ni < 4; ++ni)
        bfr[ni] = *(const bf16x8*)&Bs[wc * 64 + ni * 16 + (lane & 15)][kk + (lane >> 4) * 8];
#pragma unroll
      for (int mi = 0; mi < 4; ++mi)
#pragma unroll
        for (int ni = 0; ni < 4; ++ni)
          acc[mi][ni] = MFMA16(af[mi], bfr[ni], acc[mi][ni]);
    }
  }

#pragma unroll
  for (int ni = 0; ni < 4; ++ni) {
    int n = nbase + wc * 64 + ni * 16 + (lane & 15);
    float bv_ = bo[n];
#pragma unroll
    for (int mi = 0; mi < 4; ++mi) {
#pragma unroll
      for (int i = 0; i < 4; ++i) {
        int m = mbase + wr * 64 + mi * 16 + (lane >> 4) * 4 + i;
        outp[(size_t)m * 512 + n] = acc[mi][ni][i] + bv_;
      }
    }
  }
}

// ---------------------------------------------------------------------------
extern "C" void kernel_launch(void* const* d_in, const int* in_sizes, int n_in,
                              void* d_out, int out_size, void* d_ws, size_t ws_size,
                              hipStream_t stream) {
  const float* q_in = (const float*)d_in[0];
  const float* k_in = (const float*)d_in[1];
  const float* v_in = (const float*)d_in[2];
  const float* Wq = (const float*)d_in[3];
  const float* bq = (const float*)d_in[4];
  const float* Wk = (const float*)d_in[5];
  const float* bk = (const float*)d_in[6];
  const float* Wv = (const float*)d_in[7];
  const float* bv = (const float*)d_in[8];
  const float* Wo = (const float*)d_in[9];
  const float* bo = (const float*)d_in[10];

  float* out0 = (float*)d_out;                          // [B,S,D] f32
  float* attn = out0 + (size_t)4 * 2048 * 512;          // [B,H,S,S] f32

  unsigned short* ws = (unsigned short*)d_ws;
  const size_t SEG = (size_t)4 * 2048 * 512;
  unsigned short* q_ws  = ws;
  unsigned short* k_ws  = ws + SEG;
  unsigned short* vt_ws = ws + 2 * SEG;
  unsigned short* o_ws  = ws + 3 * SEG;

  dim3 g1(64, 4, 3);
  k_proj_qkv<<<g1, 256, 0, stream>>>(q_in, k_in, v_in, Wq, bq, Wk, bk, Wv, bv,
                                     q_ws, k_ws, vt_ws);
  dim3 g2(32, 32);
  k_attn<<<g2, 256, 0, stream>>>(q_ws, k_ws, vt_ws, o_ws, attn);
  dim3 g3(64, 4);
  k_proj_out<<<g3, 256, 0, stream>>>(o_ws, Wo, bo, out0);
}

// Round 19
// 240.305 us; speedup vs baseline: 1.2442x; 1.2442x over previous
//
#include <hip/hip_runtime.h>
#include <hip/hip_bf16.h>
#include <stdint.h>

// MHA forward: B=4, S=2048, D=512, H=8, HD=64. f32 in/out, bf16 MFMA internally.
// out0 = out [B,S,D] f32, out1 = attn [B,H,S,S] f32 (concatenated in d_out).
// k_attn: Q-block 64 rows (4 waves x 16), grid (32,32), SINGLE-buffered
// kv-64 chunks (18.4 KB LDS) + launch_bounds(256,6) -> 6 blocks/CU
// (24 waves/CU; VGPR cap 84 avoids spills — (256,8)'s cap-64 spilled, r18).
// Register prefetch; lgkm-only barriers (global loads/nt stores in flight).

typedef __attribute__((ext_vector_type(8))) short bf16x8;
typedef __attribute__((ext_vector_type(4))) short bf16x4;
typedef __attribute__((ext_vector_type(4))) float f32x4;

#define MFMA16(a, b, c) __builtin_amdgcn_mfma_f32_16x16x32_bf16((a), (b), (c), 0, 0, 0)

__device__ __forceinline__ unsigned short f2bf(float f) {
  unsigned u = __float_as_uint(f);
  u += 0x7FFFu + ((u >> 16) & 1u);   // RNE
  return (unsigned short)(u >> 16);
}
__device__ __forceinline__ float bf2f(unsigned short u) {
  return __uint_as_float(((unsigned)u) << 16);
}

// Barrier draining ONLY LDS ops; global loads / nt stores stay in flight.
__device__ __forceinline__ void lds_barrier() {
  asm volatile("s_waitcnt lgkmcnt(0)" ::: "memory");
  __builtin_amdgcn_s_barrier();
}

// ---------------------------------------------------------------------------
// Kernel 1: fused QKV projection. z = 0,1,2 -> q,k,v.
// q,k written as [B,H,S,HD] bf16; v written transposed [B,H,HD,S] bf16.
// ---------------------------------------------------------------------------
__global__ __launch_bounds__(256) void k_proj_qkv(
    const float* __restrict__ q_in, const float* __restrict__ k_in,
    const float* __restrict__ v_in,
    const float* __restrict__ Wq, const float* __restrict__ bq,
    const float* __restrict__ Wk, const float* __restrict__ bk,
    const float* __restrict__ Wv, const float* __restrict__ bv,
    unsigned short* __restrict__ q_ws, unsigned short* __restrict__ k_ws,
    unsigned short* __restrict__ vt_ws)
{
  const int z = blockIdx.z;
  const float* X    = (z == 0) ? q_in : (z == 1) ? k_in : v_in;
  const float* W    = (z == 0) ? Wq   : (z == 1) ? Wk   : Wv;
  const float* bias = (z == 0) ? bq   : (z == 1) ? bk   : bv;
  unsigned short* out = (z == 0) ? q_ws : (z == 1) ? k_ws : vt_ws;

  __shared__ unsigned short As[128][72];
  __shared__ unsigned short Bs[128][72];

  const int t = threadIdx.x;
  const int lane = t & 63;
  const int w = t >> 6;
  const int wr = w >> 1, wc = w & 1;
  const int mbase = blockIdx.x * 128;
  const int nbase = blockIdx.y * 128;

  f32x4 acc[4][4] = {};

  for (int kb = 0; kb < 512; kb += 64) {
    __syncthreads();
#pragma unroll
    for (int i = 0; i < 4; ++i) {
      int chunk = i * 256 + t;
      int row = chunk >> 3;
      int c8 = (chunk & 7) * 8;
      const float* ga = X + (size_t)(mbase + row) * 512 + kb + c8;
      float4 a0 = *(const float4*)ga;
      float4 a1 = *(const float4*)(ga + 4);
      bf16x8 pa;
      pa[0] = (short)f2bf(a0.x); pa[1] = (short)f2bf(a0.y);
      pa[2] = (short)f2bf(a0.z); pa[3] = (short)f2bf(a0.w);
      pa[4] = (short)f2bf(a1.x); pa[5] = (short)f2bf(a1.y);
      pa[6] = (short)f2bf(a1.z); pa[7] = (short)f2bf(a1.w);
      *(bf16x8*)&As[row][c8] = pa;
      const float* gb = W + (size_t)(nbase + row) * 512 + kb + c8;
      float4 b0 = *(const float4*)gb;
      float4 b1 = *(const float4*)(gb + 4);
      bf16x8 pb;
      pb[0] = (short)f2bf(b0.x); pb[1] = (short)f2bf(b0.y);
      pb[2] = (short)f2bf(b0.z); pb[3] = (short)f2bf(b0.w);
      pb[4] = (short)f2bf(b1.x); pb[5] = (short)f2bf(b1.y);
      pb[6] = (short)f2bf(b1.z); pb[7] = (short)f2bf(b1.w);
      *(bf16x8*)&Bs[row][c8] = pb;
    }
    __syncthreads();
#pragma unroll
    for (int kk = 0; kk < 64; kk += 32) {
      bf16x8 af[4], bfr[4];
#pragma unroll
      for (int mi = 0; mi < 4; ++mi)
        af[mi] = *(const bf16x8*)&As[wr * 64 + mi * 16 + (lane & 15)][kk + (lane >> 4) * 8];
#pragma unroll
      for (int ni = 0; ni < 4; ++ni)
        bfr[ni] = *(const bf16x8*)&Bs[wc * 64 + ni * 16 + (lane & 15)][kk + (lane >> 4) * 8];
#pragma unroll
      for (int mi = 0; mi < 4; ++mi)
#pragma unroll
        for (int ni = 0; ni < 4; ++ni)
          acc[mi][ni] = MFMA16(af[mi], bfr[ni], acc[mi][ni]);
    }
  }

#pragma unroll
  for (int ni = 0; ni < 4; ++ni) {
    int n = nbase + wc * 64 + ni * 16 + (lane & 15);
    float bv_ = bias[n];
    int h = n >> 6, hd = n & 63;
#pragma unroll
    for (int mi = 0; mi < 4; ++mi) {
#pragma unroll
      for (int i = 0; i < 4; ++i) {
        int m = mbase + wr * 64 + mi * 16 + (lane >> 4) * 4 + i;
        int b_ = m >> 11, s = m & 2047;
        float val = acc[mi][ni][i] + bv_;
        size_t off;
        if (z < 2) off = ((size_t)(b_ * 8 + h) * 2048 + s) * 64 + hd;      // [B,H,S,HD]
        else       off = ((size_t)(b_ * 8 + h) * 64 + hd) * 2048 + s;      // [B,H,HD,S]
        out[off] = f2bf(val);
      }
    }
  }
}

// ---------------------------------------------------------------------------
// Kernel 2: attention. Grid (32,32), 256 thr (4 waves). Single-buffered
// 64-kv chunks: regs prefetch -> LDS write -> lds_barrier -> compute ->
// lds_barrier. LDS 18.4 KB + launch_bounds(256,6) -> 6 blocks/CU.
// Wave w owns q-rows [qbase + w*16, +16). Swapped QK^T: mfma(K,Q) ->
// lane (lo=q,hi) holds 4 consecutive kv for its own q row.
// ---------------------------------------------------------------------------
__global__ __launch_bounds__(256, 6) void k_attn(
    const unsigned short* __restrict__ q_ws, const unsigned short* __restrict__ k_ws,
    const unsigned short* __restrict__ vt_ws, unsigned short* __restrict__ o_ws,
    float* __restrict__ attn_out)
{
  __shared__ unsigned short Ks[64][72];      // 9216 B
  __shared__ unsigned short Vs[64][72];      // 9216 B

  const int t = threadIdx.x;
  const int lane = t & 63;
  const int w = t >> 6;            // 0..3
  const int lo = lane & 15;
  const int hi = lane >> 4;        // 0..3
  const int bh = blockIdx.y;       // 0..31
  const int qbase = blockIdx.x * 64;
  const int qw = qbase + w * 16;   // wave's q rows
  const size_t qk_base = (size_t)bh * 2048 * 64;

  // Q fragments (B operand: col = q = lo, d = hi*8 + j)
  bf16x8 qf0 = *(const bf16x8*)(q_ws + qk_base + (size_t)(qw + lo) * 64 + hi * 8);
  bf16x8 qf1 = *(const bf16x8*)(q_ws + qk_base + (size_t)(qw + lo) * 64 + 32 + hi * 8);

  // ---------------- pass A: row sums ----------------
  float srow = 0.f;
  {
    bf16x8 gk[2];
#pragma unroll
    for (int i = 0; i < 2; ++i) {
      int flat = t + i * 256;
      gk[i] = *(const bf16x8*)(k_ws + qk_base + (size_t)(flat >> 3) * 64 + (flat & 7) * 8);
    }
    for (int c = 0; c < 32; ++c) {
#pragma unroll
      for (int i = 0; i < 2; ++i) {
        int flat = t + i * 256;
        *(bf16x8*)&Ks[flat >> 3][(flat & 7) * 8] = gk[i];
      }
      if (c < 31) {
#pragma unroll
        for (int i = 0; i < 2; ++i) {
          int flat = t + i * 256;
          gk[i] = *(const bf16x8*)(k_ws + qk_base +
                                   (size_t)((c + 1) * 64 + (flat >> 3)) * 64 + (flat & 7) * 8);
        }
      }
      lds_barrier();
#pragma unroll
      for (int t2 = 0; t2 < 4; ++t2) {
        bf16x8 kf0 = *(const bf16x8*)&Ks[t2 * 16 + lo][hi * 8];
        bf16x8 kf1 = *(const bf16x8*)&Ks[t2 * 16 + lo][32 + hi * 8];
        f32x4 cv = {};
        cv = MFMA16(kf0, qf0, cv);
        cv = MFMA16(kf1, qf1, cv);
        srow += __expf(cv[0] * 0.125f) + __expf(cv[1] * 0.125f) +
                __expf(cv[2] * 0.125f) + __expf(cv[3] * 0.125f);
      }
      lds_barrier();   // compute reads done before next chunk's writes
    }
  }
  srow += __shfl_xor(srow, 16, 64);
  srow += __shfl_xor(srow, 32, 64);
  const float rv = 1.0f / srow;    // valid for q = lo in all lanes

  // ---------------- pass B: PV + attn stores ----------------
  f32x4 o_acc[4] = {};             // [hdt]: rows q=qw+hi*4+i, col hd=hdt*16+lo
  {
    float* ao = attn_out + (size_t)bh * 2048 * 2048 +
                (size_t)(qw + lo) * 2048 + hi * 4;
    bf16x8 gk[2], gv[2];
#pragma unroll
    for (int i = 0; i < 2; ++i) {
      int flat = t + i * 256;
      gk[i] = *(const bf16x8*)(k_ws + qk_base + (size_t)(flat >> 3) * 64 + (flat & 7) * 8);
      gv[i] = *(const bf16x8*)(vt_ws + (size_t)(bh * 64 + (flat >> 3)) * 2048 + (flat & 7) * 8);
    }
    for (int c = 0; c < 32; ++c) {
#pragma unroll
      for (int i = 0; i < 2; ++i) {
        int flat = t + i * 256;
        *(bf16x8*)&Ks[flat >> 3][(flat & 7) * 8] = gk[i];
        *(bf16x8*)&Vs[flat >> 3][(flat & 7) * 8] = gv[i];
      }
      if (c < 31) {
#pragma unroll
        for (int i = 0; i < 2; ++i) {
          int flat = t + i * 256;
          gk[i] = *(const bf16x8*)(k_ws + qk_base +
                                   (size_t)((c + 1) * 64 + (flat >> 3)) * 64 + (flat & 7) * 8);
          gv[i] = *(const bf16x8*)(vt_ws + (size_t)(bh * 64 + (flat >> 3)) * 2048 +
                                   (c + 1) * 64 + (flat & 7) * 8);
        }
      }
      lds_barrier();

      unsigned pk[4][2];           // normalized bf16 pairs per t2-tile
#pragma unroll
      for (int t2 = 0; t2 < 4; ++t2) {
        bf16x8 kf0 = *(const bf16x8*)&Ks[t2 * 16 + lo][hi * 8];
        bf16x8 kf1 = *(const bf16x8*)&Ks[t2 * 16 + lo][32 + hi * 8];
        f32x4 cv = {};
        cv = MFMA16(kf0, qf0, cv);
        cv = MFMA16(kf1, qf1, cv);
        float n0 = __expf(cv[0] * 0.125f) * rv;
        float n1 = __expf(cv[1] * 0.125f) * rv;
        float n2 = __expf(cv[2] * 0.125f) * rv;
        float n3 = __expf(cv[3] * 0.125f) * rv;
        // attn store: f32x4, q-row = lo, kv = c*64 + t2*16 + hi*4
        f32x4 s; s[0] = n0; s[1] = n1; s[2] = n2; s[3] = n3;
        __builtin_nontemporal_store(s, (f32x4*)(ao + c * 64 + t2 * 16));
        pk[t2][0] = (unsigned)f2bf(n0) | ((unsigned)f2bf(n1) << 16);
        pk[t2][1] = (unsigned)f2bf(n2) | ((unsigned)f2bf(n3) << 16);
      }
      // PV: two K=32 MFMAs per hdt (ks=0: t2 0,1; ks=1: t2 2,3)
#pragma unroll
      for (int ks = 0; ks < 2; ++ks) {
        bf16x8 pa8;
        pa8[0] = (short)(pk[2 * ks][0] & 0xffffu);
        pa8[1] = (short)(pk[2 * ks][0] >> 16);
        pa8[2] = (short)(pk[2 * ks][1] & 0xffffu);
        pa8[3] = (short)(pk[2 * ks][1] >> 16);
        pa8[4] = (short)(pk[2 * ks + 1][0] & 0xffffu);
        pa8[5] = (short)(pk[2 * ks + 1][0] >> 16);
        pa8[6] = (short)(pk[2 * ks + 1][1] & 0xffffu);
        pa8[7] = (short)(pk[2 * ks + 1][1] >> 16);
#pragma unroll
        for (int hdt = 0; hdt < 4; ++hdt) {
          bf16x4 v4a = *(const bf16x4*)&Vs[hdt * 16 + lo][ks * 32 + hi * 4];
          bf16x4 v4b = *(const bf16x4*)&Vs[hdt * 16 + lo][ks * 32 + 16 + hi * 4];
          bf16x8 vb8;
          vb8[0] = v4a[0]; vb8[1] = v4a[1]; vb8[2] = v4a[2]; vb8[3] = v4a[3];
          vb8[4] = v4b[0]; vb8[5] = v4b[1]; vb8[6] = v4b[2]; vb8[7] = v4b[3];
          o_acc[hdt] = MFMA16(pa8, vb8, o_acc[hdt]);
        }
      }
      lds_barrier();
    }
  }

  // ---------------- O write (already normalized) ----------------
  {
    const int b_ = bh >> 3, h = bh & 7;
#pragma unroll
    for (int hdt = 0; hdt < 4; ++hdt)
#pragma unroll
      for (int i = 0; i < 4; ++i) {
        int q = qw + hi * 4 + i;
        o_ws[((size_t)(b_ * 2048) + q) * 512 + h * 64 + hdt * 16 + lo] =
            f2bf(o_acc[hdt][i]);
      }
  }
}

// ---------------------------------------------------------------------------
// Kernel 3: output projection, f32 out.
// ---------------------------------------------------------------------------
__global__ __launch_bounds__(256) void k_proj_out(
    const unsigned short* __restrict__ Ao, const float* __restrict__ Wo,
    const float* __restrict__ bo, float* __restrict__ outp)
{
  __shared__ unsigned short As[128][72];
  __shared__ unsigned short Bs[128][72];

  const int t = threadIdx.x;
  const int lane = t & 63;
  const int w = t >> 6;
  const int wr = w >> 1, wc = w & 1;
  const int mbase = blockIdx.x * 128;
  const int nbase = blockIdx.y * 128;

  f32x4 acc[4][4] = {};

  for (int kb = 0; kb < 512; kb += 64) {
    __syncthreads();
#pragma unroll
    for (int i = 0; i < 4; ++i) {
      int chunk = i * 256 + t;
      int row = chunk >> 3;
      int c8 = (chunk & 7) * 8;
      *(bf16x8*)&As[row][c8] =
          *(const bf16x8*)(Ao + (size_t)(mbase + row) * 512 + kb + c8);
      const float* gb = Wo + (size_t)(nbase + row) * 512 + kb + c8;
      float4 b0 = *(const float4*)gb;
      float4 b1 = *(const float4*)(gb + 4);
      bf16x8 pb;
      pb[0] = (short)f2bf(b0.x); pb[1] = (short)f2bf(b0.y);
      pb[2] = (short)f2bf(b0.z); pb[3] = (short)f2bf(b0.w);
      pb[4] = (short)f2bf(b1.x); pb[5] = (short)f2bf(b1.y);
      pb[6] = (short)f2bf(b1.z); pb[7] = (short)f2bf(b1.w);
      *(bf16x8*)&Bs[row][c8] = pb;
    }
    __syncthreads();
#pragma unroll
    for (int kk = 0; kk < 64; kk += 32) {
      bf16x8 af[4], bfr[4];
#pragma unroll
      for (int mi = 0; mi < 4; ++mi)
        af[mi] = *(const bf16x8*)&As[wr * 64 + mi * 16 + (lane & 15)][kk + (lane >> 4) * 8];
#pragma unroll
      for (int ni = 0; ni < 4; ++ni)
        bfr[ni] = *(const bf16x8*)&Bs[wc * 64 + ni * 16 + (lane & 15)][kk + (lane >> 4) * 8];
#pragma unroll
      for (int mi = 0; mi < 4; ++mi)
#pragma unroll
        for (int ni = 0; ni < 4; ++ni)
          acc[mi][ni] = MFMA16(af[mi], bfr[ni], acc[mi][ni]);
    }
  }

#pragma unroll
  for (int ni = 0; ni < 4; ++ni) {
    int n = nbase + wc * 64 + ni * 16 + (lane & 15);
    float bv_ = bo[n];
#pragma unroll
    for (int mi = 0; mi < 4; ++mi) {
#pragma unroll
      for (int i = 0; i < 4; ++i) {
        int m = mbase + wr * 64 + mi * 16 + (lane >> 4) * 4 + i;
        outp[(size_t)m * 512 + n] = acc[mi][ni][i] + bv_;
      }
    }
  }
}

// ---------------------------------------------------------------------------
extern "C" void kernel_launch(void* const* d_in, const int* in_sizes, int n_in,
                              void* d_out, int out_size, void* d_ws, size_t ws_size,
                              hipStream_t stream) {
  const float* q_in = (const float*)d_in[0];
  const float* k_in = (const float*)d_in[1];
  const float* v_in = (const float*)d_in[2];
  const float* Wq = (const float*)d_in[3];
  const float* bq = (const float*)d_in[4];
  const float* Wk = (const float*)d_in[5];
  const float* bk = (const float*)d_in[6];
  const float* Wv = (const float*)d_in[7];
  const float* bv = (const float*)d_in[8];
  const float* Wo = (const float*)d_in[9];
  const float* bo = (const float*)d_in[10];

  float* out0 = (float*)d_out;                          // [B,S,D] f32
  float* attn = out0 + (size_t)4 * 2048 * 512;          // [B,H,S,S] f32

  unsigned short* ws = (unsigned short*)d_ws;
  const size_t SEG = (size_t)4 * 2048 * 512;
  unsigned short* q_ws  = ws;
  unsigned short* k_ws  = ws + SEG;
  unsigned short* vt_ws = ws + 2 * SEG;
  unsigned short* o_ws  = ws + 3 * SEG;

  dim3 g1(64, 4, 3);
  k_proj_qkv<<<g1, 256, 0, stream>>>(q_in, k_in, v_in, Wq, bq, Wk, bk, Wv, bv,
                                     q_ws, k_ws, vt_ws);
  dim3 g2(32, 32);
  k_attn<<<g2, 256, 0, stream>>>(q_ws, k_ws, vt_ws, o_ws, attn);
  dim3 g3(64, 4);
  k_proj_out<<<g3, 256, 0, stream>>>(o_ws, Wo, bo, out0);
}